// Round 13
// baseline (313.209 us; speedup 1.0000x reference)
//
#include <hip/hip_runtime.h>

#define NPTS 16384
#define KNN 16
#define HID 64
#define NCLS 10

#define WPB 4              // waves per block (knn)
#define QPB 8              // queries per block, shared by all waves
#define CPW (NPTS / WPB)   // candidates per wave = 4096
#define SCAP 128           // per-query survivor capacity (block-shared LDS list)

// dist chain (3 fmaf): pm2 holds (-2x,-2y,-2z,|p|^2); query supplies raw (x,y,z).
// d = |p|^2 - 2 p.q  (sq_q dropped: rank-invariant per query). Identical chain
// everywhere so τ comparisons are bit-exact across phases.
__device__ __forceinline__ float distm2(float qx, float qy, float qz, float4 c) {
    return fmaf(qx, c.x, fmaf(qy, c.y, fmaf(qz, c.z, c.w)));
}

// monotone float->u32, packed with index: ascending u64 order == (d asc, j asc)
__device__ __forceinline__ unsigned long long dkey(float v, int j) {
    unsigned u = __float_as_uint(v);
    u = (u & 0x80000000u) ? ~u : (u | 0x80000000u);
    return ((unsigned long long)u << 32) | (unsigned)j;
}

__device__ __forceinline__ unsigned long long shfl_xor_u64(unsigned long long x, int m) {
    unsigned hi = (unsigned)__shfl_xor((int)(x >> 32), m, 64);
    unsigned lo = (unsigned)__shfl_xor((int)(x & 0xffffffffu), m, 64);
    return ((unsigned long long)hi << 32) | lo;
}

// exact wave-wide top-16 (overflow slow path only)
__device__ __forceinline__ void wave_top16_16(unsigned long long (&key)[16], int lane,
                                              int q, int* __restrict__ idx) {
    int outj = 0x7fffffff;
    for (int r = 0; r < 16; ++r) {
        unsigned long long gm = key[0];
#pragma unroll
        for (int s = 1; s < 16; ++s) gm = key[s] < gm ? key[s] : gm;
#pragma unroll
        for (int st = 1; st < 64; st <<= 1) {
            unsigned long long o = shfl_xor_u64(gm, st);
            gm = o < gm ? o : gm;
        }
        if (lane == r) outj = (int)(gm & 0xffffffffu);
#pragma unroll
        for (int s = 0; s < 16; ++s)
            if (key[s] == gm) key[s] = ~0ull;
    }
    if (lane < 16) idx[q * KNN + lane] = outj;
}

// pos (N,3) -> pos4 (x,y,z,|p|^2) and pm2 (-2x,-2y,-2z,|p|^2)
__global__ void prep_kernel(const float* __restrict__ pos, float4* __restrict__ pos4,
                            float4* __restrict__ pm2) {
    int i = blockIdx.x * 256 + threadIdx.x;
    if (i < NPTS) {
        float x = pos[3 * i], y = pos[3 * i + 1], z = pos[3 * i + 2];
        float sq = fmaf(x, x, fmaf(y, y, z * z));
        pos4[i] = make_float4(x, y, z, sq);
        pm2[i] = make_float4(-2.f * x, -2.f * y, -2.f * z, sq);
    }
}

// CANDIDATE-SPLIT kNN. Block = 4 waves sharing 8 queries; wave w scans its
// quarter [w*4096, (w+1)*4096) for all 8 queries -> 8192 waves (32/CU target).
// Phase A: per-lane minima over quarter; per-wave stream minima (streams =
//   j mod 16, partition full N across waves) combined in LDS -> tight tau
//   (tau = max over streams of full-N stream minima >= d16: argmins distinct).
// Phase B: tau-filtered push of (d,j) keys into block-shared per-query lists.
// Extraction: rank-select; ranks 0..15 unique under (d,j) tie-break.
// Exactly 2 block barriers.
__global__ __launch_bounds__(256) void knn_kernel(const float4* __restrict__ pos4,
                                                  const float4* __restrict__ pm2,
                                                  int* __restrict__ idx) {
    __shared__ unsigned long long keys[QPB][SCAP];   // 8KB
    __shared__ int knt[QPB];
    __shared__ float smin[QPB][WPB][16];             // 2KB
    int tid = threadIdx.x;
    int lane = tid & 63;
    int w = tid >> 6;
    int qb = blockIdx.x * QPB;
    float qx[QPB], qy[QPB], qz[QPB];
#pragma unroll
    for (int i = 0; i < QPB; ++i) {
        float4 t = pos4[qb + i];           // wave-uniform
        qx[i] = t.x; qy[i] = t.y; qz[i] = t.z;
    }
    int base = w * CPW;

    // ---- Phase A: per-lane minima over this wave's quarter (prefetched) ----
    float mn[QPB];
#pragma unroll
    for (int i = 0; i < QPB; ++i) mn[i] = INFINITY;
    {
        float4 c0 = pm2[base + lane];
        float4 c1 = pm2[base + 64 + lane];
        for (int cb = base; cb < base + CPW; cb += 128) {
            float4 n0 = pm2[cb + 128 + lane];   // pad makes last iter safe
            float4 n1 = pm2[cb + 192 + lane];
#pragma unroll
            for (int i = 0; i < QPB; ++i) mn[i] = fminf(mn[i], distm2(qx[i], qy[i], qz[i], c0));
#pragma unroll
            for (int i = 0; i < QPB; ++i) mn[i] = fminf(mn[i], distm2(qx[i], qy[i], qz[i], c1));
            c0 = n0; c1 = n1;
        }
    }
    // per-wave stream minima (stream = lane mod 16) -> LDS
#pragma unroll
    for (int i = 0; i < QPB; ++i) {
        float m = mn[i];
        m = fminf(m, __shfl_xor(m, 16, 64));
        m = fminf(m, __shfl_xor(m, 32, 64));
        if (lane < 16) smin[i][w][lane] = m;
    }
    if (tid < QPB) knt[tid] = 0;
    __syncthreads();   // barrier 1: smin + knt visible

    // tight tau from full-N stream minima (combine the 4 wave quarters)
    float tq[QPB];
#pragma unroll
    for (int i = 0; i < QPB; ++i) {
        int s = lane & 15;
        float m = fminf(fminf(smin[i][0][s], smin[i][1][s]),
                        fminf(smin[i][2][s], smin[i][3][s]));
        m = fmaxf(m, __shfl_xor(m, 1, 64));
        m = fmaxf(m, __shfl_xor(m, 2, 64));
        m = fmaxf(m, __shfl_xor(m, 4, 64));
        m = fmaxf(m, __shfl_xor(m, 8, 64));
        tq[i] = m;
    }

    // ---- Phase B: tau-filtered key push over this wave's quarter ----
    {
        float4 c0 = pm2[base + lane];
        float4 c1 = pm2[base + 64 + lane];
        for (int cb = base; cb < base + CPW; cb += 128) {
            float4 n0 = pm2[cb + 128 + lane];
            float4 n1 = pm2[cb + 192 + lane];
            int j0 = cb + lane, j1 = cb + 64 + lane;
#pragma unroll
            for (int i = 0; i < QPB; ++i) {
                float v = distm2(qx[i], qy[i], qz[i], c0);
                if (v <= tq[i]) { int s = atomicAdd(&knt[i], 1); if (s < SCAP) keys[i][s] = dkey(v, j0); }
            }
#pragma unroll
            for (int i = 0; i < QPB; ++i) {
                float v = distm2(qx[i], qy[i], qz[i], c1);
                if (v <= tq[i]) { int s = atomicAdd(&knt[i], 1); if (s < SCAP) keys[i][s] = dkey(v, j1); }
            }
            c0 = n0; c1 = n1;
        }
    }
    __syncthreads();   // barrier 2: all pushes visible

    // ---- Extraction: wave w handles queries 2w, 2w+1 ----
#pragma unroll
    for (int e = 0; e < 2; ++e) {
        int qi = w * 2 + e;
        int q = qb + qi;
        int ntot = knt[qi];
        if (ntot <= SCAP) {
            unsigned long long k0 = (lane < ntot) ? keys[qi][lane] : ~0ull;
            unsigned long long k1 = (lane + 64 < ntot) ? keys[qi][lane + 64] : ~0ull;
            int r0 = 0, r1 = 0;
            for (int t = 0; t < ntot; ++t) {
                unsigned long long k = keys[qi][t];   // broadcast ds_read
                r0 += (int)(k < k0);
                r1 += (int)(k < k1);
            }
            if (lane < ntot && r0 < KNN) idx[q * KNN + r0] = (int)(k0 & 0xffffffffu);
            if (lane + 64 < ntot && r1 < KNN) idx[q * KNN + r1] = (int)(k1 & 0xffffffffu);
        } else {
            // overflow (astronomically rare with tight tau): exact full rescan
            float tqq = tq[qi];
            unsigned long long key[16];
#pragma unroll
            for (int u = 0; u < 16; ++u) key[u] = ~0ull;
            for (int j = lane; j < NPTS; j += 64) {
                float v = distm2(qx[qi], qy[qi], qz[qi], pm2[j]);
                unsigned long long k = dkey(v, j);
                if (v <= tqq && k < key[15]) {
#pragma unroll
                    for (int s = 0; s < 16; ++s) {
                        unsigned long long a = k < key[s] ? k : key[s];
                        unsigned long long b = k < key[s] ? key[s] : k;
                        key[s] = a;
                        k = b;
                    }
                }
            }
            wave_top16_16(key, lane, q, idx);
        }
    }
}

// EdgeConv1 fully fused: h1[p][t] = relu(C + max_k xj·W1b), C = b1 + xi·(W1a-W1b).
__global__ __launch_bounds__(256) void ec1_kernel(const float4* __restrict__ pos4,
                                                  const int* __restrict__ idx,
                                                  const float* __restrict__ W1,
                                                  const float* __restrict__ b1,
                                                  float* __restrict__ h1) {
    int t = threadIdx.x & 63;
    int p = blockIdx.x * 4 + (threadIdx.x >> 6);
    float4 xi = pos4[p];
    float w0 = W1[0 * HID + t], w1 = W1[1 * HID + t], w2 = W1[2 * HID + t];
    float v0 = W1[3 * HID + t], v1 = W1[4 * HID + t], v2 = W1[5 * HID + t];
    float C = b1[t] + xi.x * (w0 - v0) + xi.y * (w1 - v1) + xi.z * (w2 - v2);
    float m = -INFINITY;
#pragma unroll
    for (int k = 0; k < KNN; ++k) {
        int j = idx[p * KNN + k];         // wave-uniform scalar load
        float4 xj = pos4[j];              // wave-uniform scalar load
        float y = fmaf(xj.x, v0, fmaf(xj.y, v1, xj.z * v2));
        m = fmaxf(m, y);
    }
    h1[p * HID + t] = fmaxf(C + m, 0.f);
}

// ec2_pre: C2[p][t] = b2 + h1[p]·(W2a-W2b) ; Y2[p][t] = h1[p]·W2b
__global__ __launch_bounds__(256) void ec2_pre_kernel(const float* __restrict__ h1,
                                                      const float* __restrict__ W2,
                                                      const float* __restrict__ b2,
                                                      float* __restrict__ C2,
                                                      float* __restrict__ Y2) {
    int t = threadIdx.x & 63;
    int r = threadIdx.x >> 6;            // 0..3
    int pb = blockIdx.x * 16 + r * 4;
    float aa[4] = {0.f, 0.f, 0.f, 0.f};
    float ab[4] = {0.f, 0.f, 0.f, 0.f};
#pragma unroll 8
    for (int f = 0; f < 64; ++f) {
        float wa = W2[f * HID + t];
        float wb = W2[(64 + f) * HID + t];
#pragma unroll
        for (int i = 0; i < 4; ++i) {
            float h = h1[(pb + i) * HID + f];   // wave-uniform broadcast
            aa[i] = fmaf(h, wa, aa[i]);
            ab[i] = fmaf(h, wb, ab[i]);
        }
    }
    float bt = b2[t];
#pragma unroll
    for (int i = 0; i < 4; ++i) {
        C2[(pb + i) * HID + t] = bt + aa[i] - ab[i];
        Y2[(pb + i) * HID + t] = ab[i];
    }
}

// ec2_maxpool: val = relu(C2 + max_k Y2[idx[k]]); block-partial max-pool.
__global__ __launch_bounds__(256) void ec2_maxpool_kernel(const float* __restrict__ C2,
                                                          const float* __restrict__ Y2,
                                                          const int* __restrict__ idx,
                                                          float* __restrict__ gpartial) {
    int t = threadIdx.x & 63;
    int lp = threadIdx.x >> 6;
    int p = blockIdx.x * 4 + lp;
    float m = -INFINITY;
#pragma unroll
    for (int k = 0; k < KNN; ++k) {
        int j = idx[p * KNN + k];
        m = fmaxf(m, Y2[j * HID + t]);
    }
    float val = fmaxf(C2[p * HID + t] + m, 0.f);
    __shared__ float red[4][64];
    red[lp][t] = val;
    __syncthreads();
    if (lp == 0) {
        float g = fmaxf(fmaxf(red[0][t], red[1][t]), fmaxf(red[2][t], red[3][t]));
        gpartial[blockIdx.x * 64 + t] = g;
    }
}

// greduce2: 4096 -> 256 partial rows, fully coalesced, 256 parallel blocks.
__global__ __launch_bounds__(256) void greduce2_kernel(const float* __restrict__ gpartial,
                                                       float* __restrict__ gp2) {
    __shared__ float red[4][64];
    int f = threadIdx.x & 63;
    int w = threadIdx.x >> 6;
    int r0 = blockIdx.x * 16 + w * 4;
    float m = -INFINITY;
#pragma unroll
    for (int r = 0; r < 4; ++r) m = fmaxf(m, gpartial[(r0 + r) * 64 + f]);
    red[w][f] = m;
    __syncthreads();
    if (w == 0)
        gp2[blockIdx.x * 64 + f] =
            fmaxf(fmaxf(red[0][f], red[1][f]), fmaxf(red[2][f], red[3][f]));
}

// tail2: 256 rows -> g[64], then linear head. One block (cheap now).
__global__ __launch_bounds__(256) void tail2_kernel(const float* __restrict__ gp2,
                                                    const float* __restrict__ Wc,
                                                    const float* __restrict__ bc,
                                                    float* __restrict__ out) {
    __shared__ float red[4][64];
    __shared__ float g[64];
    int f = threadIdx.x & 63;
    int w = threadIdx.x >> 6;
    float m = -INFINITY;
    for (int i = w; i < 256; i += 4) m = fmaxf(m, gp2[i * 64 + f]);
    red[w][f] = m;
    __syncthreads();
    if (w == 0) g[f] = fmaxf(fmaxf(red[0][f], red[1][f]), fmaxf(red[2][f], red[3][f]));
    __syncthreads();
    if (threadIdx.x < NCLS) {
        float a = bc[threadIdx.x];
#pragma unroll
        for (int h = 0; h < HID; ++h) a = fmaf(g[h], Wc[h * NCLS + threadIdx.x], a);
        out[threadIdx.x] = a;
    }
}

extern "C" void kernel_launch(void* const* d_in, const int* in_sizes, int n_in,
                              void* d_out, int out_size, void* d_ws, size_t ws_size,
                              hipStream_t stream) {
    const float* pos = (const float*)d_in[0];
    // d_in[1] = batch (all zeros, num_segments=1) -> unused
    const float* W1 = (const float*)d_in[2];
    const float* b1 = (const float*)d_in[3];
    const float* W2 = (const float*)d_in[4];
    const float* b2 = (const float*)d_in[5];
    const float* Wc = (const float*)d_in[6];
    const float* bc = (const float*)d_in[7];
    float* out = (float*)d_out;

    char* ws = (char*)d_ws;
    size_t o = 0;
    auto alloc = [&](size_t bytes) { size_t r = o; o += (bytes + 255) & ~size_t(255); return r; };
    size_t fm = (size_t)NPTS * HID * 4;
    size_t o_pos4 = alloc((size_t)NPTS * 16);
    size_t o_pm2 = alloc((size_t)(NPTS + 192) * 16);   // +192 prefetch pad
    size_t o_idx = alloc((size_t)NPTS * KNN * 4);
    size_t o_h1 = alloc(fm);
    size_t o_C2 = alloc(fm);
    size_t o_Y2 = alloc(fm);
    size_t o_gp = alloc((size_t)(NPTS / 4) * HID * 4);
    size_t o_gp2 = alloc((size_t)256 * HID * 4);

    float4* pos4 = (float4*)(ws + o_pos4);
    float4* pm2 = (float4*)(ws + o_pm2);
    int* idx = (int*)(ws + o_idx);
    float* h1 = (float*)(ws + o_h1);
    float* C2 = (float*)(ws + o_C2);
    float* Y2 = (float*)(ws + o_Y2);
    float* gp = (float*)(ws + o_gp);
    float* gp2 = (float*)(ws + o_gp2);

    // zero the prefetch pad (loaded but never consumed)
    hipMemsetAsync(pm2 + NPTS, 0, 192 * sizeof(float4), stream);

    prep_kernel<<<NPTS / 256, 256, 0, stream>>>(pos, pos4, pm2);
    knn_kernel<<<NPTS / QPB, 256, 0, stream>>>(pos4, pm2, idx);
    ec1_kernel<<<NPTS / 4, 256, 0, stream>>>(pos4, idx, W1, b1, h1);
    ec2_pre_kernel<<<NPTS / 16, 256, 0, stream>>>(h1, W2, b2, C2, Y2);
    ec2_maxpool_kernel<<<NPTS / 4, 256, 0, stream>>>(C2, Y2, idx, gp);
    greduce2_kernel<<<256, 256, 0, stream>>>(gp, gp2);
    tail2_kernel<<<1, 256, 0, stream>>>(gp2, Wc, bc, out);
}

// Round 14
// 306.197 us; speedup vs baseline: 1.0229x; 1.0229x over previous
//
#include <hip/hip_runtime.h>

#define NPTS 16384
#define KNN 16
#define HID 64
#define NCLS 10

#define WPB 4              // waves per block (knn)
#define QPB 8              // queries per block, shared by all waves
#define CPW (NPTS / WPB)   // candidates per wave = 4096
#define SCAP 128           // per-query survivor capacity (block-shared LDS list)

// dist chain (3 fmaf): pm2 holds (-2x,-2y,-2z,|p|^2); query supplies raw (x,y,z).
// d = |p|^2 - 2 p.q  (sq_q dropped: rank-invariant per query). Identical chain
// everywhere so τ comparisons are bit-exact across phases.
__device__ __forceinline__ float distm2(float qx, float qy, float qz, float4 c) {
    return fmaf(qx, c.x, fmaf(qy, c.y, fmaf(qz, c.z, c.w)));
}

// monotone float->u32, packed with index: ascending u64 order == (d asc, j asc)
__device__ __forceinline__ unsigned long long dkey(float v, int j) {
    unsigned u = __float_as_uint(v);
    u = (u & 0x80000000u) ? ~u : (u | 0x80000000u);
    return ((unsigned long long)u << 32) | (unsigned)j;
}

__device__ __forceinline__ unsigned long long shfl_xor_u64(unsigned long long x, int m) {
    unsigned hi = (unsigned)__shfl_xor((int)(x >> 32), m, 64);
    unsigned lo = (unsigned)__shfl_xor((int)(x & 0xffffffffu), m, 64);
    return ((unsigned long long)hi << 32) | lo;
}

// exact wave-wide top-16 (overflow slow path only)
__device__ __forceinline__ void wave_top16_16(unsigned long long (&key)[16], int lane,
                                              int q, int* __restrict__ idx) {
    int outj = 0x7fffffff;
    for (int r = 0; r < 16; ++r) {
        unsigned long long gm = key[0];
#pragma unroll
        for (int s = 1; s < 16; ++s) gm = key[s] < gm ? key[s] : gm;
#pragma unroll
        for (int st = 1; st < 64; st <<= 1) {
            unsigned long long o = shfl_xor_u64(gm, st);
            gm = o < gm ? o : gm;
        }
        if (lane == r) outj = (int)(gm & 0xffffffffu);
#pragma unroll
        for (int s = 0; s < 16; ++s)
            if (key[s] == gm) key[s] = ~0ull;
    }
    if (lane < 16) idx[q * KNN + lane] = outj;
}

// pos (N,3) -> pos4 (x,y,z,|p|^2) and pm2 (-2x,-2y,-2z,|p|^2)
__global__ void prep_kernel(const float* __restrict__ pos, float4* __restrict__ pos4,
                            float4* __restrict__ pm2) {
    int i = blockIdx.x * 256 + threadIdx.x;
    if (i < NPTS) {
        float x = pos[3 * i], y = pos[3 * i + 1], z = pos[3 * i + 2];
        float sq = fmaf(x, x, fmaf(y, y, z * z));
        pos4[i] = make_float4(x, y, z, sq);
        pm2[i] = make_float4(-2.f * x, -2.f * y, -2.f * z, sq);
    }
}

// CANDIDATE-SPLIT kNN (R13 structure) + 2-deep prefetch + merged branch tests.
// Block = 4 waves sharing 8 queries; wave w scans its quarter for all 8.
// Phase A: per-lane minima; per-wave stream minima combined in LDS -> tight tau.
// Phase B: tau-filtered push of (d,j) keys into block-shared per-query lists.
// Extraction: rank-select; ranks 0..15 unique under (d,j) tie-break. 2 barriers.
__global__ __launch_bounds__(256) void knn_kernel(const float4* __restrict__ pos4,
                                                  const float4* __restrict__ pm2,
                                                  int* __restrict__ idx) {
    __shared__ unsigned long long keys[QPB][SCAP];   // 8KB
    __shared__ int knt[QPB];
    __shared__ float smin[QPB][WPB][16];             // 2KB
    int tid = threadIdx.x;
    int lane = tid & 63;
    int w = tid >> 6;
    int qb = blockIdx.x * QPB;
    float qx[QPB], qy[QPB], qz[QPB];
#pragma unroll
    for (int i = 0; i < QPB; ++i) {
        float4 t = pos4[qb + i];           // wave-uniform
        qx[i] = t.x; qy[i] = t.y; qz[i] = t.z;
    }
    int base = w * CPW;

    // ---- Phase A: per-lane minima, 2-deep register prefetch ----
    float mn[QPB];
#pragma unroll
    for (int i = 0; i < QPB; ++i) mn[i] = INFINITY;
    {
        float4 c0 = pm2[base + lane],       c1 = pm2[base + 64 + lane];
        float4 d0 = pm2[base + 128 + lane], d1 = pm2[base + 192 + lane];
        for (int cb = base; cb < base + CPW; cb += 128) {
#pragma unroll
            for (int i = 0; i < QPB; ++i) mn[i] = fminf(mn[i], distm2(qx[i], qy[i], qz[i], c0));
#pragma unroll
            for (int i = 0; i < QPB; ++i) mn[i] = fminf(mn[i], distm2(qx[i], qy[i], qz[i], c1));
            c0 = d0; c1 = d1;
            d0 = pm2[cb + 256 + lane];      // pad (+256) makes last iters safe
            d1 = pm2[cb + 320 + lane];
        }
    }
    // per-wave stream minima (stream = lane mod 16) -> LDS
#pragma unroll
    for (int i = 0; i < QPB; ++i) {
        float m = mn[i];
        m = fminf(m, __shfl_xor(m, 16, 64));
        m = fminf(m, __shfl_xor(m, 32, 64));
        if (lane < 16) smin[i][w][lane] = m;
    }
    if (tid < QPB) knt[tid] = 0;
    __syncthreads();   // barrier 1: smin + knt visible

    // tight tau from full-N stream minima (combine the 4 wave quarters)
    float tq[QPB];
#pragma unroll
    for (int i = 0; i < QPB; ++i) {
        int s = lane & 15;
        float m = fminf(fminf(smin[i][0][s], smin[i][1][s]),
                        fminf(smin[i][2][s], smin[i][3][s]));
        m = fmaxf(m, __shfl_xor(m, 1, 64));
        m = fmaxf(m, __shfl_xor(m, 2, 64));
        m = fmaxf(m, __shfl_xor(m, 4, 64));
        m = fmaxf(m, __shfl_xor(m, 8, 64));
        tq[i] = m;
    }

    // ---- Phase B: tau-filtered push, merged (2-candidate) branch tests ----
    {
        float4 c0 = pm2[base + lane],       c1 = pm2[base + 64 + lane];
        float4 d0 = pm2[base + 128 + lane], d1 = pm2[base + 192 + lane];
        for (int cb = base; cb < base + CPW; cb += 128) {
            int j0 = cb + lane, j1 = cb + 64 + lane;
#pragma unroll
            for (int i = 0; i < QPB; ++i) {
                float va = distm2(qx[i], qy[i], qz[i], c0);
                float vb = distm2(qx[i], qy[i], qz[i], c1);
                if (fminf(va, vb) <= tq[i]) {           // 8 branches/iter not 16
                    if (va <= tq[i]) { int s = atomicAdd(&knt[i], 1); if (s < SCAP) keys[i][s] = dkey(va, j0); }
                    if (vb <= tq[i]) { int s = atomicAdd(&knt[i], 1); if (s < SCAP) keys[i][s] = dkey(vb, j1); }
                }
            }
            c0 = d0; c1 = d1;
            d0 = pm2[cb + 256 + lane];
            d1 = pm2[cb + 320 + lane];
        }
    }
    __syncthreads();   // barrier 2: all pushes visible

    // ---- Extraction: wave w handles queries 2w, 2w+1 ----
#pragma unroll
    for (int e = 0; e < 2; ++e) {
        int qi = w * 2 + e;
        int q = qb + qi;
        int ntot = knt[qi];
        if (ntot <= SCAP) {
            unsigned long long k0 = (lane < ntot) ? keys[qi][lane] : ~0ull;
            unsigned long long k1 = (lane + 64 < ntot) ? keys[qi][lane + 64] : ~0ull;
            int r0 = 0, r1 = 0;
            for (int t = 0; t < ntot; ++t) {
                unsigned long long k = keys[qi][t];   // broadcast ds_read
                r0 += (int)(k < k0);
                r1 += (int)(k < k1);
            }
            if (lane < ntot && r0 < KNN) idx[q * KNN + r0] = (int)(k0 & 0xffffffffu);
            if (lane + 64 < ntot && r1 < KNN) idx[q * KNN + r1] = (int)(k1 & 0xffffffffu);
        } else {
            // overflow (astronomically rare with tight tau): exact full rescan
            float tqq = tq[qi];
            unsigned long long key[16];
#pragma unroll
            for (int u = 0; u < 16; ++u) key[u] = ~0ull;
            for (int j = lane; j < NPTS; j += 64) {
                float v = distm2(qx[qi], qy[qi], qz[qi], pm2[j]);
                unsigned long long k = dkey(v, j);
                if (v <= tqq && k < key[15]) {
#pragma unroll
                    for (int s = 0; s < 16; ++s) {
                        unsigned long long a = k < key[s] ? k : key[s];
                        unsigned long long b = k < key[s] ? key[s] : k;
                        key[s] = a;
                        k = b;
                    }
                }
            }
            wave_top16_16(key, lane, q, idx);
        }
    }
}

// FUSED EdgeConv1 + ec2_pre (both pointwise in p; h1 never touches global).
// Wave handles 4 points: compute h1 into LDS, then C2/Y2 from LDS broadcasts.
__global__ __launch_bounds__(256) void ec12_kernel(const float4* __restrict__ pos4,
                                                   const int* __restrict__ idx,
                                                   const float* __restrict__ W1,
                                                   const float* __restrict__ b1,
                                                   const float* __restrict__ W2,
                                                   const float* __restrict__ b2,
                                                   float* __restrict__ C2,
                                                   float* __restrict__ Y2) {
    __shared__ float h1s[16][64];    // 4KB, [w*4+i][t], wave-private slices
    int t = threadIdx.x & 63;
    int w = threadIdx.x >> 6;
    int pb = blockIdx.x * 16 + w * 4;
    float w0 = W1[0 * HID + t], w1 = W1[1 * HID + t], w2 = W1[2 * HID + t];
    float v0 = W1[3 * HID + t], v1 = W1[4 * HID + t], v2 = W1[5 * HID + t];
    float bt1 = b1[t];
#pragma unroll
    for (int i = 0; i < 4; ++i) {
        int p = pb + i;
        float4 xi = pos4[p];
        float C = bt1 + xi.x * (w0 - v0) + xi.y * (w1 - v1) + xi.z * (w2 - v2);
        float m = -INFINITY;
#pragma unroll
        for (int k = 0; k < KNN; ++k) {
            int j = idx[p * KNN + k];     // wave-uniform scalar load
            float4 xj = pos4[j];          // wave-uniform scalar load
            m = fmaxf(m, fmaf(xj.x, v0, fmaf(xj.y, v1, xj.z * v2)));
        }
        h1s[w * 4 + i][t] = fmaxf(C + m, 0.f);
    }
    __syncthreads();
    float aa[4] = {0.f, 0.f, 0.f, 0.f};
    float ab[4] = {0.f, 0.f, 0.f, 0.f};
#pragma unroll 8
    for (int f = 0; f < 64; ++f) {
        float wa = W2[f * HID + t];
        float wb = W2[(64 + f) * HID + t];
#pragma unroll
        for (int i = 0; i < 4; ++i) {
            float h = h1s[w * 4 + i][f];   // broadcast ds_read
            aa[i] = fmaf(h, wa, aa[i]);
            ab[i] = fmaf(h, wb, ab[i]);
        }
    }
    float bt = b2[t];
#pragma unroll
    for (int i = 0; i < 4; ++i) {
        C2[(pb + i) * HID + t] = bt + aa[i] - ab[i];
        Y2[(pb + i) * HID + t] = ab[i];
    }
}

// ec2_maxpool: val = relu(C2 + max_k Y2[idx[k]]); block-partial max-pool.
__global__ __launch_bounds__(256) void ec2_maxpool_kernel(const float* __restrict__ C2,
                                                          const float* __restrict__ Y2,
                                                          const int* __restrict__ idx,
                                                          float* __restrict__ gpartial) {
    int t = threadIdx.x & 63;
    int lp = threadIdx.x >> 6;
    int p = blockIdx.x * 4 + lp;
    float m = -INFINITY;
#pragma unroll
    for (int k = 0; k < KNN; ++k) {
        int j = idx[p * KNN + k];
        m = fmaxf(m, Y2[j * HID + t]);
    }
    float val = fmaxf(C2[p * HID + t] + m, 0.f);
    __shared__ float red[4][64];
    red[lp][t] = val;
    __syncthreads();
    if (lp == 0) {
        float g = fmaxf(fmaxf(red[0][t], red[1][t]), fmaxf(red[2][t], red[3][t]));
        gpartial[blockIdx.x * 64 + t] = g;
    }
}

// greduce2: 4096 -> 256 partial rows, fully coalesced, 256 parallel blocks.
__global__ __launch_bounds__(256) void greduce2_kernel(const float* __restrict__ gpartial,
                                                       float* __restrict__ gp2) {
    __shared__ float red[4][64];
    int f = threadIdx.x & 63;
    int w = threadIdx.x >> 6;
    int r0 = blockIdx.x * 16 + w * 4;
    float m = -INFINITY;
#pragma unroll
    for (int r = 0; r < 4; ++r) m = fmaxf(m, gpartial[(r0 + r) * 64 + f]);
    red[w][f] = m;
    __syncthreads();
    if (w == 0)
        gp2[blockIdx.x * 64 + f] =
            fmaxf(fmaxf(red[0][f], red[1][f]), fmaxf(red[2][f], red[3][f]));
}

// tail2: 256 rows -> g[64], then linear head. One block (cheap now).
__global__ __launch_bounds__(256) void tail2_kernel(const float* __restrict__ gp2,
                                                    const float* __restrict__ Wc,
                                                    const float* __restrict__ bc,
                                                    float* __restrict__ out) {
    __shared__ float red[4][64];
    __shared__ float g[64];
    int f = threadIdx.x & 63;
    int w = threadIdx.x >> 6;
    float m = -INFINITY;
    for (int i = w; i < 256; i += 4) m = fmaxf(m, gp2[i * 64 + f]);
    red[w][f] = m;
    __syncthreads();
    if (w == 0) g[f] = fmaxf(fmaxf(red[0][f], red[1][f]), fmaxf(red[2][f], red[3][f]));
    __syncthreads();
    if (threadIdx.x < NCLS) {
        float a = bc[threadIdx.x];
#pragma unroll
        for (int h = 0; h < HID; ++h) a = fmaf(g[h], Wc[h * NCLS + threadIdx.x], a);
        out[threadIdx.x] = a;
    }
}

extern "C" void kernel_launch(void* const* d_in, const int* in_sizes, int n_in,
                              void* d_out, int out_size, void* d_ws, size_t ws_size,
                              hipStream_t stream) {
    const float* pos = (const float*)d_in[0];
    // d_in[1] = batch (all zeros, num_segments=1) -> unused
    const float* W1 = (const float*)d_in[2];
    const float* b1 = (const float*)d_in[3];
    const float* W2 = (const float*)d_in[4];
    const float* b2 = (const float*)d_in[5];
    const float* Wc = (const float*)d_in[6];
    const float* bc = (const float*)d_in[7];
    float* out = (float*)d_out;

    char* ws = (char*)d_ws;
    size_t o = 0;
    auto alloc = [&](size_t bytes) { size_t r = o; o += (bytes + 255) & ~size_t(255); return r; };
    size_t fm = (size_t)NPTS * HID * 4;
    size_t o_pos4 = alloc((size_t)NPTS * 16);
    size_t o_pm2 = alloc((size_t)(NPTS + 320) * 16);   // +320 prefetch pad
    size_t o_idx = alloc((size_t)NPTS * KNN * 4);
    size_t o_C2 = alloc(fm);
    size_t o_Y2 = alloc(fm);
    size_t o_gp = alloc((size_t)(NPTS / 4) * HID * 4);
    size_t o_gp2 = alloc((size_t)256 * HID * 4);

    float4* pos4 = (float4*)(ws + o_pos4);
    float4* pm2 = (float4*)(ws + o_pm2);
    int* idx = (int*)(ws + o_idx);
    float* C2 = (float*)(ws + o_C2);
    float* Y2 = (float*)(ws + o_Y2);
    float* gp = (float*)(ws + o_gp);
    float* gp2 = (float*)(ws + o_gp2);

    // zero the prefetch pad (loaded but never consumed)
    hipMemsetAsync(pm2 + NPTS, 0, 320 * sizeof(float4), stream);

    prep_kernel<<<NPTS / 256, 256, 0, stream>>>(pos, pos4, pm2);
    knn_kernel<<<NPTS / QPB, 256, 0, stream>>>(pos4, pm2, idx);
    ec12_kernel<<<NPTS / 16, 256, 0, stream>>>(pos4, idx, W1, b1, W2, b2, C2, Y2);
    ec2_maxpool_kernel<<<NPTS / 4, 256, 0, stream>>>(C2, Y2, idx, gp);
    greduce2_kernel<<<256, 256, 0, stream>>>(gp, gp2);
    tail2_kernel<<<1, 256, 0, stream>>>(gp2, Wc, bc, out);
}